// Round 13
// baseline (41.804 us; speedup 1.0000x reference)
//
#include <hip/hip_runtime.h>
#include <math.h>

#define HD 512
#define WD 512
#define NP 255            // patch grid = 255 x 255
#define LK 7225           // patches per kk group; 7225 = 85*85
#define BATCH 32
#define RB 85             // r's per chunk (765 ll = exactly 3 pi2-rows)
#define CH 85
#define NTHR 576          // 9 waves: wave k = kk group k (wave-aligned -> no conflicts)
#define ROWF 144          // parity-plane row length (h=0: 144 used; h=1: 136)
#define PLT 2016          // floats per tensor: even 7*144 + odd 7*144
#define NWG (BATCH * CH * 2)   // 5440 (div by 8 -> clean XCD swizzle)

// Semantics (reference's flat reshape (b,9,L)->(b,L,9)):
//   l = kk*7225 + r ; (di,dj) = (kk/3, kk%3) fixed within a 9-group
//   k in 0..8: ll = 9r+k -> pixel (2*(ll/255)+di, 2*(ll%255)+dj)
//   argmin/argmax |a-c| (first-occurrence), s = c[argmin]+c[argmax]
//   broadcast to 2x2 (3x3 at edges) block of patch (l/255, l%255); row/col 511 = 0.
//
// R12 = R11 with kk groups WAVE-ALIGNED (R11's 5.65M bank-conflict cycles came
// from two kk groups sharing a wave: second group's banks = first's shifted by
// 16 -> 3-4 way collisions on all 27 reads). Wave k owns kk=k; a single-kk
// wave reads banks (di*16 + 9m + j) mod 32 -> <=2-way (free). 9 waves x 64;
// 3 blocks/CU = 27 waves/CU. Staging (contiguous parity-plane b128 writes),
// wrap (+289), and epilogue identical to R11 (verified absmax 0).
// h=0: pj2<128 (43 m), stages cols [0,288). h=1: pj2>=128 (42 m), stages
// cols [256,512) + 16-col wrap strip.

__global__ __launch_bounds__(NTHR) void dc_pool_kernel(
    const float* __restrict__ anchor,
    const float* __restrict__ pos,
    const float* __restrict__ neg,
    float* __restrict__ out0,
    float* __restrict__ out1)
{
    __shared__ float lds[3 * PLT];   // A | P | N ; each: even[7][144] odd[7][144]

    // XCD-aware swizzle (bijective: NWG % 8 == 0); halves of a chunk adjacent.
    int bid = blockIdx.x;
    int vid = (bid & 7) * (NWG / 8) + (bid >> 3);
    int h     = vid & 1;
    int rest  = vid >> 1;
    int chunk = rest % CH;
    int b     = rest / CH;

    const size_t plane = (size_t)HD * WD;
    const float* A = anchor + (size_t)b * plane;
    const float* P = pos    + (size_t)b * plane;
    const float* N = neg    + (size_t)b * plane;
    float* O0 = out0 + (size_t)b * plane;
    float* O1 = out1 + (size_t)b * plane;

    int tid  = threadIdx.x;
    int row0 = 6 * chunk;             // first staged image row (max 510)

    // ---- stage: 32B chunk per lane -> 1 even-b128 + 1 odd-b128 ds_write ----
    // per tensor: h=0: 7 rows x 36 chunks (cols [0,288))             = 252
    //             h=1: 7 rows x 34 chunks ([256,512) + strip [0,16)) = 238
    int perRow = h ? 34 : 36;
    int perT   = 7 * perRow;
    int NC     = 3 * perT;            // 756 / 714  (<= 2*NTHR)
    #pragma unroll
    for (int J = 0; J < 2; ++J) {
        int u = J * NTHR + tid;
        if (u < NC) {
            int t   = u / perT;
            int rem = u - t * perT;
            int rr  = rem / perRow;
            int w   = rem - rr * perRow;
            int col0, ent;
            if (!h)          { col0 = 8 * w;          ent = 4 * w; }
            else if (w < 32) { col0 = 256 + 8 * w;    ent = 4 * w; }
            else             { col0 = 8 * (w - 32);   ent = 128 + 4 * (w - 32); }
            const float* g = (t == 0 ? A : (t == 1 ? P : N))
                             + (size_t)(row0 + rr) * WD + col0;
            float4 a0 = *reinterpret_cast<const float4*>(g);
            float4 a1 = *reinterpret_cast<const float4*>(g + 4);
            int e = t * PLT + rr * ROWF + ent;
            *reinterpret_cast<float4*>(&lds[e])        = make_float4(a0.x, a0.z, a1.x, a1.z);
            *reinterpret_cast<float4*>(&lds[e + 1008]) = make_float4(a0.y, a0.w, a1.y, a1.w);
        }
    }
    __syncthreads();

    // ---- compute: wave = kk, lane = gi ; single kk per wave -> conflict-free ----
    int NGM = 43 - h;                 // m's in this half
    int kk  = tid >> 6;               // 0..8
    int gi  = tid & 63;
    if (gi >= NGM) return;
    int di = kk / 3;
    int dj = kk - 3 * di;

    int j, m;
    if (!h) { j = (gi < 15) ? 0 : ((gi < 29) ? 1 : 2);
              m = gi + ((gi < 15) ? 0 : ((gi < 29) ? 14 : 28)); }
    else    { j = (gi < 14) ? 0 : ((gi < 28) ? 1 : 2);
              m = gi + ((gi < 14) ? 15 : ((gi < 28) ? 29 : 43)); }
    int pj2 = 9 * m - 255 * j;
    int r   = chunk * RB + m;
    int rr  = 2 * j + di;

    int pb    = (dj == 1) ? 1008 : 0;   // odd plane for dj=1, else even
    int base0 = pb + rr * ROWF + pj2 - (h ? 128 : 0) + ((dj == 2) ? 1 : 0);
    int wrapk = NP - pj2;               // <9 only in h=1 (pj2>=247)

    float minvP = 0.f, maxvP = 0.f, mindP = INFINITY, maxdP = -INFINITY;
    float minvN = 0.f, maxvN = 0.f, mindN = INFINITY, maxdN = -INFINITY;
    #pragma unroll
    for (int k = 0; k < 9; ++k) {
        int lo = base0 + k + ((k >= wrapk) ? 289 : 0);  // wrap: +2 rows, strip
        float a = lds[lo];
        float p = lds[PLT + lo];
        float n = lds[2 * PLT + lo];
        float dp = fabsf(a - p);
        float dn = fabsf(a - n);
        if (dp < mindP) { mindP = dp; minvP = p; }   // first-occurrence argmin
        if (dp > maxdP) { maxdP = dp; maxvP = p; }   // first-occurrence argmax
        if (dn < mindN) { mindN = dn; minvN = n; }
        if (dn > maxdN) { maxdN = dn; maxvN = n; }
    }
    float s0 = minvP + maxvP;
    float s1 = minvN + maxvN;

    // ---- scatter to output (consecutive gi -> consecutive float2) ----
    int l   = kk * LK + r;
    int piy = l / NP;
    int pjx = l - piy * NP;
    int y0  = 2 * piy;
    int x0  = 2 * pjx;
    bool right  = (pjx == NP - 1);
    bool bottom = (piy == NP - 1);
    int ny = bottom ? 3 : 2;

    for (int yy = 0; yy < ny; ++yy) {
        float* p0 = O0 + (size_t)(y0 + yy) * WD + x0;
        float* p1 = O1 + (size_t)(y0 + yy) * WD + x0;
        if (right) {    // cols 508,509,510 = s ; col 511 = 0
            *reinterpret_cast<float4*>(p0) = make_float4(s0, s0, s0, 0.f);
            *reinterpret_cast<float4*>(p1) = make_float4(s1, s1, s1, 0.f);
        } else {
            *reinterpret_cast<float2*>(p0) = make_float2(s0, s0);
            *reinterpret_cast<float2*>(p1) = make_float2(s1, s1);
        }
    }
    if (bottom) {       // row 511 = 0
        float* p0 = O0 + (size_t)(HD - 1) * WD + x0;
        float* p1 = O1 + (size_t)(HD - 1) * WD + x0;
        if (right) {
            *reinterpret_cast<float4*>(p0) = make_float4(0.f, 0.f, 0.f, 0.f);
            *reinterpret_cast<float4*>(p1) = make_float4(0.f, 0.f, 0.f, 0.f);
        } else {
            *reinterpret_cast<float2*>(p0) = make_float2(0.f, 0.f);
            *reinterpret_cast<float2*>(p1) = make_float2(0.f, 0.f);
        }
    }
}

extern "C" void kernel_launch(void* const* d_in, const int* in_sizes, int n_in,
                              void* d_out, int out_size, void* d_ws, size_t ws_size,
                              hipStream_t stream) {
    const float* anchor = (const float*)d_in[0];
    const float* pos    = (const float*)d_in[1];
    const float* neg    = (const float*)d_in[2];
    float* out0 = (float*)d_out;
    float* out1 = out0 + (size_t)BATCH * HD * WD;

    dc_pool_kernel<<<NWG, NTHR, 0, stream>>>(anchor, pos, neg, out0, out1);
}

// Round 14
// 41.470 us; speedup vs baseline: 1.0081x; 1.0081x over previous
//
#include <hip/hip_runtime.h>
#include <math.h>

#define HD 512
#define WD 512
#define NP 255            // patch grid = 255 x 255
#define LK 7225           // patches per kk group; 7225 = 85*85
#define BATCH 32
#define RB 85             // r's per chunk (765 ll = exactly 3 pi2-rows)
#define CH 85
#define NTHR 384          // 6 waves, ALL in staging and compute
#define ROWF 144          // parity-plane row length (h=0: 144 used; h=1: 136)
#define PLT 2016          // floats per tensor: even 7*144 + odd 7*144
#define NWG (BATCH * CH * 2)   // 5440 (div by 8 -> clean XCD swizzle)

// Semantics (reference's flat reshape (b,9,L)->(b,L,9)):
//   l = kk*7225 + r ; (di,dj) = (kk/3, kk%3) fixed within a 9-group
//   k in 0..8: ll = 9r+k -> pixel (2*(ll/255)+di, 2*(ll%255)+dj)
//   argmin/argmax |a-c| (first-occurrence), s = c[argmin]+c[argmax]
//   broadcast to 2x2 (3x3 at edges) block of patch (l/255, l%255); row/col 511 = 0.
//
// R13 = R11 with dj-INNERMOST compute mapping (lane = (di*NGM+gi)*3 + dj).
// R11's kk-major mapping put two kk groups per wave offset by 1008 (≡16 mod
// 32) -> systematic 3-4-way bank conflicts (5.65M cycles). R12 (wave-aligned
// kk) fixed banks but idled 21/64 lanes -> net loss. dj-innermost keeps ALL
// lanes active AND spreads reads: stride-9 clusters (coprime 32) x dj offsets
// {0,+16,+1} -> only 6 colliding lane-pairs per wave read. Staging, parity
// planes, wrap (+289), epilogue identical to R11 (verified absmax 0).
// h=0: pj2<128 (43 m), stages cols [0,288). h=1: pj2>=128 (42 m), stages
// cols [256,512) + 16-col wrap strip.

__global__ __launch_bounds__(NTHR) void dc_pool_kernel(
    const float* __restrict__ anchor,
    const float* __restrict__ pos,
    const float* __restrict__ neg,
    float* __restrict__ out0,
    float* __restrict__ out1)
{
    __shared__ float lds[3 * PLT];   // A | P | N ; each: even[7][144] odd[7][144]

    // XCD-aware swizzle (bijective: NWG % 8 == 0); halves of a chunk adjacent.
    int bid = blockIdx.x;
    int vid = (bid & 7) * (NWG / 8) + (bid >> 3);
    int h     = vid & 1;
    int rest  = vid >> 1;
    int chunk = rest % CH;
    int b     = rest / CH;

    const size_t plane = (size_t)HD * WD;
    const float* A = anchor + (size_t)b * plane;
    const float* P = pos    + (size_t)b * plane;
    const float* N = neg    + (size_t)b * plane;
    float* O0 = out0 + (size_t)b * plane;
    float* O1 = out1 + (size_t)b * plane;

    int tid  = threadIdx.x;
    int row0 = 6 * chunk;             // first staged image row (max 510)

    // ---- stage: 32B chunk per lane -> 1 even-b128 + 1 odd-b128 ds_write ----
    // per tensor: h=0: 7 rows x 36 chunks (cols [0,288))             = 252
    //             h=1: 7 rows x 34 chunks ([256,512) + strip [0,16)) = 238
    int perRow = h ? 34 : 36;
    int perT   = 7 * perRow;
    int NC     = 3 * perT;            // 756 / 714  (<= 2*NTHR)
    #pragma unroll
    for (int J = 0; J < 2; ++J) {
        int u = J * NTHR + tid;
        if (u < NC) {
            int t   = u / perT;
            int rem = u - t * perT;
            int rr  = rem / perRow;
            int w   = rem - rr * perRow;
            int col0, ent;
            if (!h)          { col0 = 8 * w;          ent = 4 * w; }
            else if (w < 32) { col0 = 256 + 8 * w;    ent = 4 * w; }
            else             { col0 = 8 * (w - 32);   ent = 128 + 4 * (w - 32); }
            const float* g = (t == 0 ? A : (t == 1 ? P : N))
                             + (size_t)(row0 + rr) * WD + col0;
            float4 a0 = *reinterpret_cast<const float4*>(g);
            float4 a1 = *reinterpret_cast<const float4*>(g + 4);
            int e = t * PLT + rr * ROWF + ent;
            *reinterpret_cast<float4*>(&lds[e])        = make_float4(a0.x, a0.z, a1.x, a1.z);
            *reinterpret_cast<float4*>(&lds[e + 1008]) = make_float4(a0.y, a0.w, a1.y, a1.w);
        }
    }
    __syncthreads();

    // ---- compute: one group per lane, dj innermost (bank-friendly) ----
    int NGM   = 43 - h;               // m's in this half
    int total = 9 * NGM;              // 387 / 378
    for (int glane = tid; glane < total; glane += NTHR) {
        int dj      = glane % 3;
        int cluster = glane / 3;      // 0 .. 3*NGM-1
        int di      = cluster / NGM;
        int gi      = cluster - di * NGM;
        int kk      = 3 * di + dj;

        int j, m;
        if (!h) { j = (gi < 15) ? 0 : ((gi < 29) ? 1 : 2);
                  m = gi + ((gi < 15) ? 0 : ((gi < 29) ? 14 : 28)); }
        else    { j = (gi < 14) ? 0 : ((gi < 28) ? 1 : 2);
                  m = gi + ((gi < 14) ? 15 : ((gi < 28) ? 29 : 43)); }
        int pj2 = 9 * m - 255 * j;
        int r   = chunk * RB + m;
        int rr  = 2 * j + di;

        int pb    = (dj == 1) ? 1008 : 0;   // odd plane for dj=1, else even
        int base0 = pb + rr * ROWF + pj2 - (h ? 128 : 0) + ((dj == 2) ? 1 : 0);
        int wrapk = NP - pj2;               // <9 only in h=1 (pj2>=247)

        float minvP = 0.f, maxvP = 0.f, mindP = INFINITY, maxdP = -INFINITY;
        float minvN = 0.f, maxvN = 0.f, mindN = INFINITY, maxdN = -INFINITY;
        #pragma unroll
        for (int k = 0; k < 9; ++k) {
            int lo = base0 + k + ((k >= wrapk) ? 289 : 0);  // wrap: +2 rows, strip
            float a = lds[lo];
            float p = lds[PLT + lo];
            float n = lds[2 * PLT + lo];
            float dp = fabsf(a - p);
            float dn = fabsf(a - n);
            if (dp < mindP) { mindP = dp; minvP = p; }   // first-occurrence argmin
            if (dp > maxdP) { maxdP = dp; maxvP = p; }   // first-occurrence argmax
            if (dn < mindN) { mindN = dn; minvN = n; }
            if (dn > maxdN) { maxdN = dn; maxvN = n; }
        }
        float s0 = minvP + maxvP;
        float s1 = minvN + maxvN;

        // ---- scatter to output (3 coalesced ~21-lane streams per wave) ----
        int l   = kk * LK + r;
        int piy = l / NP;
        int pjx = l - piy * NP;
        int y0  = 2 * piy;
        int x0  = 2 * pjx;
        bool right  = (pjx == NP - 1);
        bool bottom = (piy == NP - 1);
        int ny = bottom ? 3 : 2;

        for (int yy = 0; yy < ny; ++yy) {
            float* p0 = O0 + (size_t)(y0 + yy) * WD + x0;
            float* p1 = O1 + (size_t)(y0 + yy) * WD + x0;
            if (right) {    // cols 508,509,510 = s ; col 511 = 0
                *reinterpret_cast<float4*>(p0) = make_float4(s0, s0, s0, 0.f);
                *reinterpret_cast<float4*>(p1) = make_float4(s1, s1, s1, 0.f);
            } else {
                *reinterpret_cast<float2*>(p0) = make_float2(s0, s0);
                *reinterpret_cast<float2*>(p1) = make_float2(s1, s1);
            }
        }
        if (bottom) {       // row 511 = 0
            float* p0 = O0 + (size_t)(HD - 1) * WD + x0;
            float* p1 = O1 + (size_t)(HD - 1) * WD + x0;
            if (right) {
                *reinterpret_cast<float4*>(p0) = make_float4(0.f, 0.f, 0.f, 0.f);
                *reinterpret_cast<float4*>(p1) = make_float4(0.f, 0.f, 0.f, 0.f);
            } else {
                *reinterpret_cast<float2*>(p0) = make_float2(0.f, 0.f);
                *reinterpret_cast<float2*>(p1) = make_float2(0.f, 0.f);
            }
        }
    }
}

extern "C" void kernel_launch(void* const* d_in, const int* in_sizes, int n_in,
                              void* d_out, int out_size, void* d_ws, size_t ws_size,
                              hipStream_t stream) {
    const float* anchor = (const float*)d_in[0];
    const float* pos    = (const float*)d_in[1];
    const float* neg    = (const float*)d_in[2];
    float* out0 = (float*)d_out;
    float* out1 = out0 + (size_t)BATCH * HD * WD;

    dc_pool_kernel<<<NWG, NTHR, 0, stream>>>(anchor, pos, neg, out0, out1);
}

// Round 15
// 37.408 us; speedup vs baseline: 1.1175x; 1.1086x over previous
//
#include <hip/hip_runtime.h>
#include <math.h>

#define HD 512
#define WD 512
#define NP 255            // patch grid = 255 x 255
#define LK 7225           // patches per kk group; 7225 = 85*85
#define BATCH 32
#define RB 85             // r's per chunk (765 ll = exactly 3 pi2-rows)
#define CH 85
#define NTHR 448          // 7 waves; single compute pass (387/378 groups)
#define ROWF 160          // parity-plane row stride; 160 % 32 == 0 -> rr drops out of bank math
#define PB1  1132         // odd-plane base: 7*160=1120 (+12); 12 mod 32 spreads planes, mod 4 = 0
#define PLT  2252         // floats per tensor (1132 + 1120)
#define NWG (BATCH * CH * 2)   // 5440 (div by 8 -> clean XCD swizzle)

// Semantics (reference's flat reshape (b,9,L)->(b,L,9)):
//   l = kk*7225 + r ; (di,dj) = (kk/3, kk%3) fixed within a 9-group
//   k in 0..8: ll = 9r+k -> pixel (2*(ll/255)+di, 2*(ll%255)+dj)
//   argmin/argmax |a-c| (first-occurrence), s = c[argmin]+c[argmax]
//   broadcast to 2x2 (3x3 at edges) block of patch (l/255, l%255); row/col 511 = 0.
//
// R14 = R11 with the bank geometry fixed BY CONSTRUCTION:
//   R11's conflicts came from ROWF=144 (== 16 mod 32) and plane offset
//   1008 (== 16 mod 32) double-aligning two kk runs in each wave.
//   Now ROWF == 0 mod 32 (row term vanishes) and odd plane at +12 mod 32
//   (stride-9 run of 2nd kk group lands on the single-coverage banks of the
//   1st; ~1-3 residual 3-way banks). Plus NTHR=448: one compute pass (R11
//   wasted a full serial pass on 3 leftover lanes). Staging/wrap/epilogue
//   logic identical to verified R11 (wrap bump re-derived: +321 = 2*ROWF+1).
// h=0: pj2<128 (43 m), stages cols [0,288). h=1: pj2>=128 (42 m), stages
// cols [256,512) + 16-col wrap strip at entries 128..135 (read only via wrap).

__global__ __launch_bounds__(NTHR) void dc_pool_kernel(
    const float* __restrict__ anchor,
    const float* __restrict__ pos,
    const float* __restrict__ neg,
    float* __restrict__ out0,
    float* __restrict__ out1)
{
    __shared__ float lds[3 * PLT];   // A | P | N ; each: even[7][160] | odd[7][160] @ +1132

    // XCD-aware swizzle (bijective: NWG % 8 == 0); halves of a chunk adjacent.
    int bid = blockIdx.x;
    int vid = (bid & 7) * (NWG / 8) + (bid >> 3);
    int h     = vid & 1;
    int rest  = vid >> 1;
    int chunk = rest % CH;
    int b     = rest / CH;

    const size_t plane = (size_t)HD * WD;
    const float* A = anchor + (size_t)b * plane;
    const float* P = pos    + (size_t)b * plane;
    const float* N = neg    + (size_t)b * plane;
    float* O0 = out0 + (size_t)b * plane;
    float* O1 = out1 + (size_t)b * plane;

    int tid  = threadIdx.x;
    int row0 = 6 * chunk;             // first staged image row (max 510)

    // ---- stage: 32B chunk per lane -> 1 even-b128 + 1 odd-b128 ds_write ----
    // per tensor: h=0: 7 rows x 36 chunks (cols [0,288))             = 252
    //             h=1: 7 rows x 34 chunks ([256,512) + strip [0,16)) = 238
    int perRow = h ? 34 : 36;
    int perT   = 7 * perRow;
    int NC     = 3 * perT;            // 756 / 714  (<= 2*NTHR)
    #pragma unroll
    for (int J = 0; J < 2; ++J) {
        int u = J * NTHR + tid;
        if (u < NC) {
            int t   = u / perT;
            int rem = u - t * perT;
            int rr  = rem / perRow;
            int w   = rem - rr * perRow;
            int col0, ent;
            if (!h)          { col0 = 8 * w;          ent = 4 * w; }
            else if (w < 32) { col0 = 256 + 8 * w;    ent = 4 * w; }
            else             { col0 = 8 * (w - 32);   ent = 128 + 4 * (w - 32); }
            const float* g = (t == 0 ? A : (t == 1 ? P : N))
                             + (size_t)(row0 + rr) * WD + col0;
            float4 a0 = *reinterpret_cast<const float4*>(g);
            float4 a1 = *reinterpret_cast<const float4*>(g + 4);
            int e = t * PLT + rr * ROWF + ent;
            *reinterpret_cast<float4*>(&lds[e])       = make_float4(a0.x, a0.z, a1.x, a1.z);
            *reinterpret_cast<float4*>(&lds[e + PB1]) = make_float4(a0.y, a0.w, a1.y, a1.w);
        }
    }
    __syncthreads();

    // ---- compute: one (kk, gi) group per lane; lane = kk*NGM + gi (1 pass) ----
    int NGM   = 43 - h;               // m's in this half
    int total = 9 * NGM;              // 387 / 378  (<= NTHR)
    if (tid < total) {
        int kk = tid / NGM;
        int gi = tid - kk * NGM;
        int di = kk / 3;
        int dj = kk - 3 * di;

        int j, m;
        if (!h) { j = (gi < 15) ? 0 : ((gi < 29) ? 1 : 2);
                  m = gi + ((gi < 15) ? 0 : ((gi < 29) ? 14 : 28)); }
        else    { j = (gi < 14) ? 0 : ((gi < 28) ? 1 : 2);
                  m = gi + ((gi < 14) ? 15 : ((gi < 28) ? 29 : 43)); }
        int pj2 = 9 * m - 255 * j;
        int r   = chunk * RB + m;
        int rr  = 2 * j + di;

        int pb    = (dj == 1) ? PB1 : 0;    // odd plane for dj=1, else even
        int base0 = pb + rr * ROWF + pj2 - (h ? 128 : 0) + ((dj == 2) ? 1 : 0);
        int wrapk = NP - pj2;               // <9 only in h=1 (pj2>=247)

        float minvP = 0.f, maxvP = 0.f, mindP = INFINITY, maxdP = -INFINITY;
        float minvN = 0.f, maxvN = 0.f, mindN = INFINITY, maxdN = -INFINITY;
        #pragma unroll
        for (int k = 0; k < 9; ++k) {
            int lo = base0 + k + ((k >= wrapk) ? (2 * ROWF + 1) : 0);  // wrap: +2 rows, strip
            float a = lds[lo];
            float p = lds[PLT + lo];
            float n = lds[2 * PLT + lo];
            float dp = fabsf(a - p);
            float dn = fabsf(a - n);
            if (dp < mindP) { mindP = dp; minvP = p; }   // first-occurrence argmin
            if (dp > maxdP) { maxdP = dp; maxvP = p; }   // first-occurrence argmax
            if (dn < mindN) { mindN = dn; minvN = n; }
            if (dn > maxdN) { maxdN = dn; maxvN = n; }
        }
        float s0 = minvP + maxvP;
        float s1 = minvN + maxvN;

        // ---- scatter to output (consecutive gi -> consecutive float2) ----
        int l   = kk * LK + r;
        int piy = l / NP;
        int pjx = l - piy * NP;
        int y0  = 2 * piy;
        int x0  = 2 * pjx;
        bool right  = (pjx == NP - 1);
        bool bottom = (piy == NP - 1);
        int ny = bottom ? 3 : 2;

        for (int yy = 0; yy < ny; ++yy) {
            float* p0 = O0 + (size_t)(y0 + yy) * WD + x0;
            float* p1 = O1 + (size_t)(y0 + yy) * WD + x0;
            if (right) {    // cols 508,509,510 = s ; col 511 = 0
                *reinterpret_cast<float4*>(p0) = make_float4(s0, s0, s0, 0.f);
                *reinterpret_cast<float4*>(p1) = make_float4(s1, s1, s1, 0.f);
            } else {
                *reinterpret_cast<float2*>(p0) = make_float2(s0, s0);
                *reinterpret_cast<float2*>(p1) = make_float2(s1, s1);
            }
        }
        if (bottom) {       // row 511 = 0
            float* p0 = O0 + (size_t)(HD - 1) * WD + x0;
            float* p1 = O1 + (size_t)(HD - 1) * WD + x0;
            if (right) {
                *reinterpret_cast<float4*>(p0) = make_float4(0.f, 0.f, 0.f, 0.f);
                *reinterpret_cast<float4*>(p1) = make_float4(0.f, 0.f, 0.f, 0.f);
            } else {
                *reinterpret_cast<float2*>(p0) = make_float2(0.f, 0.f);
                *reinterpret_cast<float2*>(p1) = make_float2(0.f, 0.f);
            }
        }
    }
}

extern "C" void kernel_launch(void* const* d_in, const int* in_sizes, int n_in,
                              void* d_out, int out_size, void* d_ws, size_t ws_size,
                              hipStream_t stream) {
    const float* anchor = (const float*)d_in[0];
    const float* pos    = (const float*)d_in[1];
    const float* neg    = (const float*)d_in[2];
    float* out0 = (float*)d_out;
    float* out1 = out0 + (size_t)BATCH * HD * WD;

    dc_pool_kernel<<<NWG, NTHR, 0, stream>>>(anchor, pos, neg, out0, out1);
}

// Round 16
// 35.091 us; speedup vs baseline: 1.1913x; 1.0660x over previous
//
#include <hip/hip_runtime.h>
#include <math.h>

#define HD 512
#define WD 512
#define NP 255            // patch grid = 255 x 255
#define LK 7225           // patches per kk group; 7225 = 85*85
#define BATCH 32
#define RB 85             // r's per chunk (765 ll = exactly 3 pi2-rows)
#define CH 85
#define NTHR 448          // 7 waves; single compute pass (387/378 groups)
#define TCOLS 288         // native row layout; h=0 cols [0,288); h=1 [240,512)+strip
#define TENF (7 * TCOLS)  // 2016 floats per tensor (24192 B total LDS)
#define NF4  1512         // 3 tensors x 7 rows x 72 float4
#define NWG (BATCH * CH * 2)   // 5440 (div by 8 -> clean XCD swizzle)

// Semantics (reference's flat reshape (b,9,L)->(b,L,9)):
//   l = kk*7225 + r ; (di,dj) = (kk/3, kk%3) fixed within a 9-group
//   k in 0..8: ll = 9r+k -> pixel (2*(ll/255)+di, 2*(ll%255)+dj)
//   argmin/argmax |a-c| (first-occurrence), s = c[argmin]+c[argmax]
//   broadcast to 2x2 (3x3 at edges) block of patch (l/255, l%255); row/col 511 = 0.
//
// R15 = assembly of measured-best parts only:
//  - R8 half-chunk geometry + contiguous 7-row fetch + XCD swizzle (FETCH 49MB)
//  - global_load_lds direct staging, NATIVE [7][288] layout (R6/R7's stride-2
//    read pattern measured 2.0 cyc/wave-read vs parity layouts' 5.8)
//  - R14 single-pass kk-major compute: 448 thr, one (kk,gi) group per lane
//    (verified decode; stores stay gi-consecutive = coalesced float2)
//  - wrap bump +578 (R8-verified): pj2>=247 reads strip entries [272,288) two
//    rows down. h=0 never wraps.
// 4 blocks/CU (wave-capped: 7 waves x 4 = 28), LDS 24.2 KB.

typedef const __attribute__((address_space(1))) void* gp1_t;
typedef __attribute__((address_space(3))) void* lp3_t;

__global__ __launch_bounds__(NTHR) void dc_pool_kernel(
    const float* __restrict__ anchor,
    const float* __restrict__ pos,
    const float* __restrict__ neg,
    float* __restrict__ out0,
    float* __restrict__ out1)
{
    __shared__ float lds[3 * TENF];   // A | P | N ; each [7][288] native cols

    // XCD-aware swizzle (bijective: NWG % 8 == 0); halves of a chunk adjacent.
    int bid = blockIdx.x;
    int vid = (bid & 7) * (NWG / 8) + (bid >> 3);
    int h     = vid & 1;
    int rest  = vid >> 1;
    int chunk = rest % CH;
    int b     = rest / CH;

    const size_t plane = (size_t)HD * WD;
    const float* A = anchor + (size_t)b * plane;
    const float* P = pos    + (size_t)b * plane;
    const float* N = neg    + (size_t)b * plane;
    float* O0 = out0 + (size_t)b * plane;
    float* O1 = out1 + (size_t)b * plane;

    int tid   = threadIdx.x;
    int wbase = tid & ~63;
    int row0  = 6 * chunk;            // first staged image row (max 510)

    // ---- stage 7 rows x 72 f4 x 3 tensors = 1512 x 16B via global_load_lds ----
    // u -> tensor u/504, row (u%504)/72, c4 (u%504)%72 ; LDS dst linear in u.
    // h=0: gcol4 = c4 (cols [0,288)).
    // h=1: c4<68 -> gcol4 = 60+c4 (cols [240,512)); c4>=68 -> strip cols [0,16)
    //      at entries [272,288).
    #pragma unroll
    for (int J = 0; J < 4; ++J) {
        int u = J * NTHR + tid;
        if (u < NF4) {
            int t   = u / 504;
            int rem = u - t * 504;
            int rr  = rem / 72;
            int c4  = rem - rr * 72;
            int g4  = (h == 0) ? c4 : (c4 < 68 ? 60 + c4 : c4 - 68);
            const float* g = (t == 0 ? A : (t == 1 ? P : N))
                             + (size_t)(row0 + rr) * WD + g4 * 4;
            float* l = &lds[(size_t)(J * NTHR + wbase) * 4];
            __builtin_amdgcn_global_load_lds((gp1_t)(const void*)g,
                                             (lp3_t)(void*)l, 16, 0, 0);
        }
    }
    __syncthreads();   // drains vmcnt; one-shot block

    // ---- compute: one (kk, gi) group per lane; lane = kk*NGM + gi (1 pass) ----
    int NGM   = 43 - h;               // m's in this half
    int total = 9 * NGM;              // 387 / 378  (<= NTHR)
    if (tid < total) {
        int kk = tid / NGM;
        int gi = tid - kk * NGM;
        int di = kk / 3;
        int dj = kk - 3 * di;

        int j, m;
        if (!h) { j = (gi < 15) ? 0 : ((gi < 29) ? 1 : 2);
                  m = gi + ((gi < 15) ? 0 : ((gi < 29) ? 14 : 28)); }
        else    { j = (gi < 14) ? 0 : ((gi < 28) ? 1 : 2);
                  m = gi + ((gi < 14) ? 15 : ((gi < 28) ? 29 : 43)); }
        int pj2 = 9 * m - 255 * j;    // h=0: [0,126] ; h=1: [129,252]
        int r   = chunk * RB + m;
        int rr  = 2 * j + di;

        int base0 = rr * TCOLS + 2 * pj2 + dj - (h ? 240 : 0);
        int wrapk = NP - pj2;         // <=8 only in h=1 (pj2>=247)

        float minvP = 0.f, maxvP = 0.f, mindP = INFINITY, maxdP = -INFINITY;
        float minvN = 0.f, maxvN = 0.f, mindN = INFINITY, maxdN = -INFINITY;
        #pragma unroll
        for (int k = 0; k < 9; ++k) {
            int lo = base0 + 2 * k + ((k >= wrapk) ? 578 : 0);  // wrap: +2 rows, strip
            float a = lds[lo];
            float p = lds[TENF + lo];
            float n = lds[2 * TENF + lo];
            float dp = fabsf(a - p);
            float dn = fabsf(a - n);
            if (dp < mindP) { mindP = dp; minvP = p; }   // first-occurrence argmin
            if (dp > maxdP) { maxdP = dp; maxvP = p; }   // first-occurrence argmax
            if (dn < mindN) { mindN = dn; minvN = n; }
            if (dn > maxdN) { maxdN = dn; maxvN = n; }
        }
        float s0 = minvP + maxvP;
        float s1 = minvN + maxvN;

        // ---- scatter to output (consecutive gi -> consecutive float2) ----
        int l   = kk * LK + r;
        int piy = l / NP;
        int pjx = l - piy * NP;
        int y0  = 2 * piy;
        int x0  = 2 * pjx;
        bool right  = (pjx == NP - 1);
        bool bottom = (piy == NP - 1);
        int ny = bottom ? 3 : 2;

        for (int yy = 0; yy < ny; ++yy) {
            float* p0 = O0 + (size_t)(y0 + yy) * WD + x0;
            float* p1 = O1 + (size_t)(y0 + yy) * WD + x0;
            if (right) {    // cols 508,509,510 = s ; col 511 = 0
                *reinterpret_cast<float4*>(p0) = make_float4(s0, s0, s0, 0.f);
                *reinterpret_cast<float4*>(p1) = make_float4(s1, s1, s1, 0.f);
            } else {
                *reinterpret_cast<float2*>(p0) = make_float2(s0, s0);
                *reinterpret_cast<float2*>(p1) = make_float2(s1, s1);
            }
        }
        if (bottom) {       // row 511 = 0
            float* p0 = O0 + (size_t)(HD - 1) * WD + x0;
            float* p1 = O1 + (size_t)(HD - 1) * WD + x0;
            if (right) {
                *reinterpret_cast<float4*>(p0) = make_float4(0.f, 0.f, 0.f, 0.f);
                *reinterpret_cast<float4*>(p1) = make_float4(0.f, 0.f, 0.f, 0.f);
            } else {
                *reinterpret_cast<float2*>(p0) = make_float2(0.f, 0.f);
                *reinterpret_cast<float2*>(p1) = make_float2(0.f, 0.f);
            }
        }
    }
}

extern "C" void kernel_launch(void* const* d_in, const int* in_sizes, int n_in,
                              void* d_out, int out_size, void* d_ws, size_t ws_size,
                              hipStream_t stream) {
    const float* anchor = (const float*)d_in[0];
    const float* pos    = (const float*)d_in[1];
    const float* neg    = (const float*)d_in[2];
    float* out0 = (float*)d_out;
    float* out1 = out0 + (size_t)BATCH * HD * WD;

    dc_pool_kernel<<<NWG, NTHR, 0, stream>>>(anchor, pos, neg, out0, out1);
}